// Round 8
// baseline (55.857 us; speedup 1.0000x reference)
//
#include <hip/hip_runtime.h>

// out[b,o,c,l] = time[b,c,l] * sum_{i,k} W[o,i,c,k] * x[b,i,c,l+k-1]  (x zero-padded in l)
// b=16, i=64, c=4, L=4096, o=64, K=3
//
// DIAGNOSTIC ROUND: dispatch order = prepack, ablate_rw (memory skeleton,
// garbage into d_out), tconv_mfma (r7 kernel, unchanged, overwrites d_out
// correctly). V_rw duration = bench_dur - 33.5us. Ablation has identical
// grid/LDS/load/store patterns but no LDS round-trip / barrier / MFMA.

#define NB 16
#define NI 64
#define NC 4
#define NL 4096
#define NO 64
#define KW 3
#define LT 64
#define NT 4
#define LBLK (LT * NT)        // 256 l per block
#define ROWS (LBLK + 2)       // 258
#define ROWB 128              // 64 i * 2B
#define TOFF (ROWS * ROWB)    // time region offset (33024)
#define LDSB (TOFF + LBLK * 4)

#define W_PACK_BYTES (NO * NI * NC * KW * 2)   // 98304

typedef float f32x4 __attribute__((ext_vector_type(4)));
typedef short bf16x8 __attribute__((ext_vector_type(8)));
typedef unsigned int u32x2 __attribute__((ext_vector_type(2)));

__device__ inline unsigned short f2bf(float f) {
    unsigned int u = __builtin_bit_cast(unsigned int, f);
    u += 0x7FFFu + ((u >> 16) & 1u);          // round-to-nearest-even
    return (unsigned short)(u >> 16);
}

__device__ __forceinline__ void block_sync_lds() {
    asm volatile("s_waitcnt lgkmcnt(0)" ::: "memory");
    __builtin_amdgcn_s_barrier();
    asm volatile("" ::: "memory");
}

// ---- kernel 1: pack W (coalesced read, scattered 2B write) ----
__global__ __launch_bounds__(256)
void prepack_w_kernel(const float* __restrict__ w, unsigned short* __restrict__ wp) {
    const int idx = blockIdx.x * 256 + threadIdx.x;      // 49152 = o*i*c*k
    const float v = w[idx];                              // coalesced
    const int k = idx % 3;
    int r = idx / 3;
    const int c = r & 3;  r >>= 2;
    const int i = r & 63;
    const int o = r >> 6;
    const int cc   = k * 2 + (i >> 5);
    const int lane = (((i >> 3) & 3) << 4) | (o & 15);
    const int j    = i & 7;
    const int wv   = o >> 4;
    wp[(((c * 4 + wv) * 6 + cc) * 64 + lane) * 8 + j] = f2bf(v);
}

// staging task: quad = lane&15 (l-quad), g = wave*4 + (lane>>4) (i-group of 4)
__device__ __forceinline__ void stage_load(const float* __restrict__ xb,
                                           int l0, int g, f32x4 s[4]) {
    const float* p = xb + (size_t)(4 * g) * (NC * NL) + l0;
    s[0] = *(const f32x4*)(p);
    s[1] = *(const f32x4*)(p + NC * NL);
    s[2] = *(const f32x4*)(p + 2 * NC * NL);
    s[3] = *(const f32x4*)(p + 3 * NC * NL);
}

// ---- ABLATION: pure memory skeleton. Same grid, same LDS footprint,
// same x-load addresses, same out-store addresses. No barrier/LDS-RT/MFMA.
__global__ __launch_bounds__(256, 4)
void ablate_rw_kernel(const float* __restrict__ x,
                      const float* __restrict__ tt,
                      float* __restrict__ out)
{
    __shared__ char lds[LDSB];                           // occupancy-matched

    const int t    = threadIdx.x;
    const int lane = t & 63;
    const int wave = t >> 6;
    const int c    = blockIdx.y;
    const int b    = blockIdx.z;
    const int lb0  = blockIdx.x * LBLK;
    const int o0   = wave * 16;
    const int g    = wave * 4 + (lane >> 4);
    const int lq   = 4 * (lane & 15);

    const float* xb = x + ((size_t)b * NI * NC + c) * NL;
    const float* tb = tt + (size_t)(b * NC + c) * NL;
    float* ob = out + ((size_t)b * NO * NC + (size_t)(o0 + (lane & 15)) * NC + c) * NL;

    ((volatile char*)lds)[t] = (char)t;                  // pin LDS allocation

    f32x4 s[4][4];
    stage_load(xb, lb0 + 0 * LT + lq, g, s[0]);
    stage_load(xb, lb0 + 1 * LT + lq, g, s[1]);
    stage_load(xb, lb0 + 2 * LT + lq, g, s[2]);
    stage_load(xb, lb0 + 3 * LT + lq, g, s[3]);
    const float tval = tb[lb0 + t];

#pragma unroll
    for (int tch = 0; tch < 4; ++tch) {
#pragma unroll
        for (int lt = 0; lt < 4; ++lt) {
            const int l0 = lb0 + tch * LT + lt * 16 + (lane >> 4) * 4;
            f32x4 r = s[tch][lt];
            r[0] += tval;                                // dependency: store waits loads
            *(f32x4*)(ob + l0) = r;
        }
    }
}

__device__ __forceinline__ void stage_write(char* __restrict__ lds,
                                            int r0, int g, const f32x4 s[4]) {
#pragma unroll
    for (int r = 0; r < 4; ++r) {
        const int rr = r0 + r;
        u32x2 pk;
        pk[0] = (unsigned int)f2bf(s[0][r]) | ((unsigned int)f2bf(s[1][r]) << 16);
        pk[1] = (unsigned int)f2bf(s[2][r]) | ((unsigned int)f2bf(s[3][r]) << 16);
        *(u32x2*)(lds + rr * ROWB + ((8 * g) ^ ((rr & 7) << 4))) = pk;
    }
}

__device__ __forceinline__ void compute_store(const char* __restrict__ lds,
                                              const bf16x8 wfrag[6],
                                              float* __restrict__ ob,
                                              int t, int lb0, int lane) {
    const int lcol  = lane & 15;
    const int ksub2 = (lane >> 4) * 16;

    f32x4 tv[4];
#pragma unroll
    for (int lt = 0; lt < 4; ++lt)
        tv[lt] = *(const f32x4*)(lds + TOFF + 4 * (t * LT + lt * 16 + (lane >> 4) * 4));

    f32x4 acc[4] = {};
#pragma unroll
    for (int lt = 0; lt < 4; ++lt) {
#pragma unroll
        for (int cc = 0; cc < 6; ++cc) {
            const int k    = cc >> 1;
            const int ih   = cc & 1;
            const int row  = t * LT + lt * 16 + lcol + k;
            const int colb = ih * 64 + ksub2;
            const int off  = row * ROWB + (colb ^ ((row & 7) << 4));
            const bf16x8 xf = *(const bf16x8*)(lds + off);
            acc[lt] = __builtin_amdgcn_mfma_f32_16x16x32_bf16(xf, wfrag[cc], acc[lt], 0, 0, 0);
        }
    }
#pragma unroll
    for (int lt = 0; lt < 4; ++lt) {
        const int l0 = lb0 + t * LT + lt * 16 + (lane >> 4) * 4;
        f32x4 r;
#pragma unroll
        for (int q = 0; q < 4; ++q) r[q] = acc[lt][q] * tv[lt][q];
        *(f32x4*)(ob + l0) = r;
    }
}

__global__ __launch_bounds__(256, 4)
void tconv_mfma_kernel(const float* __restrict__ x,
                       const float* __restrict__ tt,
                       const unsigned short* __restrict__ wp,
                       float* __restrict__ out)
{
    __shared__ char lds[LDSB];                           // 34 048 B

    const int t    = threadIdx.x;
    const int lane = t & 63;
    const int wave = t >> 6;
    const int c    = blockIdx.y;
    const int b    = blockIdx.z;
    const int lb0  = blockIdx.x * LBLK;
    const int o0   = wave * 16;
    const int g    = wave * 4 + (lane >> 4);
    const int lq   = 4 * (lane & 15);

    const float* xb = x + ((size_t)b * NI * NC + c) * NL;
    const float* tb = tt + (size_t)(b * NC + c) * NL;
    float* ob = out + ((size_t)b * NO * NC + (size_t)(o0 + (lane & 15)) * NC + c) * NL;

    // ---- prologue: x chunks 0,1 + halo + time issue first
    f32x4 s0[4], s1[4];
    stage_load(xb, lb0 + 0 * LT + lq, g, s0);
    stage_load(xb, lb0 + 1 * LT + lq, g, s1);
    float h = 0.f; int hrow = 0, hcol = 0;
    if (t < 128) {
        const int which = t & 1;
        const int i     = t >> 1;
        hrow = which ? (LBLK + 1) : 0;
        hcol = 2 * i;
        const int lh = which ? (lb0 + LBLK) : (lb0 - 1);
        if (lh >= 0 && lh < NL) h = xb[(size_t)i * (NC * NL) + lh];
    }
    const float tval = tb[lb0 + t];

    // ---- W fragments: 6 coalesced b128, L2-hot
    bf16x8 wfrag[6];
    {
        const bf16x8* wpb = (const bf16x8*)wp + (size_t)((c * 4 + wave) * 6) * 64 + lane;
#pragma unroll
        for (int cc = 0; cc < 6; ++cc) wfrag[cc] = wpb[cc * 64];
    }

    // ---- writes for chunks 0,1 + halo + time
    stage_write(lds, 1 + 0 * LT + lq, g, s0);
    stage_write(lds, 1 + 1 * LT + lq, g, s1);
    if (t < 128)
        *(unsigned short*)(lds + hrow * ROWB + (hcol ^ ((hrow & 7) << 4))) = f2bf(h);
    *(float*)(lds + TOFF + 4 * t) = tval;
    block_sync_lds();

    // ---- deep prefetch: chunks 2 AND 3 in flight before any compute
    stage_load(xb, lb0 + 2 * LT + lq, g, s0);
    stage_load(xb, lb0 + 3 * LT + lq, g, s1);

    compute_store(lds, wfrag, ob, 0, lb0, lane);
    stage_write(lds, 1 + 2 * LT + lq, g, s0);
    block_sync_lds();

    compute_store(lds, wfrag, ob, 1, lb0, lane);
    stage_write(lds, 1 + 3 * LT + lq, g, s1);
    block_sync_lds();

    // ---- drain
    compute_store(lds, wfrag, ob, 2, lb0, lane);
    compute_store(lds, wfrag, ob, 3, lb0, lane);
}

extern "C" void kernel_launch(void* const* d_in, const int* in_sizes, int n_in,
                              void* d_out, int out_size, void* d_ws, size_t ws_size,
                              hipStream_t stream) {
    const float* x  = (const float*)d_in[0];
    const float* tt = (const float*)d_in[1];
    const float* w  = (const float*)d_in[2];
    float* out = (float*)d_out;
    unsigned short* wpck = (unsigned short*)d_ws;

    dim3 block(256);
    dim3 grid(NL / LBLK, NC, NB);   // (16, 4, 16) = 1024 blocks

    prepack_w_kernel<<<dim3(NO * NI * NC * KW / 256), block, 0, stream>>>(w, wpck);
    ablate_rw_kernel<<<grid, block, 0, stream>>>(x, tt, out);          // garbage
    tconv_mfma_kernel<<<grid, block, 0, stream>>>(x, tt, wpck, out);   // overwrites
}

// Round 9
// 46.436 us; speedup vs baseline: 1.2029x; 1.2029x over previous
//
#include <hip/hip_runtime.h>

// out[b,o,c,l] = time[b,c,l] * sum_{i,k} W[o,i,c,k] * x[b,i,c,l+k-1]  (x zero-padded in l)
// b=16, i=64, c=4, L=4096, o=64, K=3
//
// BARRIER-FREE wave-private structure (r8 ablation: memory skeleton = 5.7 TB/s,
// so the barrier-locked phase structure was the stall). Each wave owns a
// private 128-l strip = 4 chunks of 32 l, double-buffered in its OWN LDS
// region; pipeline load(t+1) -> compute(t) -> write(t+1) with zero s_barrier.
// Wave computes all 64 o (x-fragment reused over 4 o-strips: 12 ds_read ->
// 48 MFMA per chunk). W prepacked to fragment order (24 b128, L2-hot).

#define NB 16
#define NI 64
#define NC 4
#define NL 4096
#define NO 64
#define KW 3
#define CL 32                 // chunk length (l)
#define NCH 4                 // chunks per wave
#define WL (CL * NCH)         // 128 l per wave
#define WAVES 2               // waves per block
#define BLKL (WL * WAVES)     // 256 l per block
#define BROWS (CL + 2)        // 34 rows (halo 1 each side)
#define ROWB 128              // 64 i * 2B bf16
#define BUFB (BROWS * ROWB)   // 4352 B per buffer

#define W_PACK_BYTES (NO * NI * NC * KW * 2)   // 98304

typedef float f32x4 __attribute__((ext_vector_type(4)));
typedef short bf16x8 __attribute__((ext_vector_type(8)));
typedef unsigned int u32x4 __attribute__((ext_vector_type(4)));

__device__ inline unsigned short f2bf(float f) {
    unsigned int u = __builtin_bit_cast(unsigned int, f);
    u += 0x7FFFu + ((u >> 16) & 1u);          // round-to-nearest-even
    return (unsigned short)(u >> 16);
}

// ---- kernel 1: pack W (coalesced read, scattered 2B write) ----
// dest flat bf16 index = (((c*4 + wv)*6 + cc)*64 + lane)*8 + j  where
// o = wv*16 + (lane&15), i = (cc&1)*32 + (lane>>4)*8 + j, k = cc>>1
__global__ __launch_bounds__(256)
void prepack_w_kernel(const float* __restrict__ w, unsigned short* __restrict__ wp) {
    const int idx = blockIdx.x * 256 + threadIdx.x;      // 49152 = o*i*c*k
    const float v = w[idx];                              // coalesced
    const int k = idx % 3;
    int r = idx / 3;
    const int c = r & 3;  r >>= 2;
    const int i = r & 63;
    const int o = r >> 6;
    const int cc   = k * 2 + (i >> 5);
    const int lane = (((i >> 3) & 3) << 4) | (o & 15);
    const int j    = i & 7;
    const int wv   = o >> 4;
    wp[(((c * 4 + wv) * 6 + cc) * 64 + lane) * 8 + j] = f2bf(v);
}

// ---- staging: wave-private chunk of 32 l x 64 i ----
// q = lane&7 (l-quad within chunk), gi = lane>>3 (i-octet)
__device__ __forceinline__ void stage_load(const float* __restrict__ xb,
                                           int l0, int lane,
                                           f32x4 v[8], float h[2]) {
    const int q  = lane & 7;
    const int gi = lane >> 3;
    const float* p = xb + (size_t)(8 * gi) * (NC * NL) + l0 + 4 * q;
#pragma unroll
    for (int ii = 0; ii < 8; ++ii)
        v[ii] = *(const f32x4*)(p + (size_t)ii * (NC * NL));
    // halo: i = lane, rows l0-1 and l0+CL
    const float* ph = xb + (size_t)lane * (NC * NL);
    h[0] = (l0 - 1 >= 0) ? ph[l0 - 1] : 0.f;
    h[1] = (l0 + CL < NL) ? ph[l0 + CL] : 0.f;
}

__device__ __forceinline__ void stage_write(char* __restrict__ buf, int lane,
                                            const f32x4 v[8], const float h[2]) {
    const int q  = lane & 7;
    const int gi = lane >> 3;
#pragma unroll
    for (int r = 0; r < 4; ++r) {
        const int row = 4 * q + r + 1;                   // rows 1..32
        u32x4 pk;
#pragma unroll
        for (int w2 = 0; w2 < 4; ++w2)
            pk[w2] = (unsigned int)f2bf(v[2 * w2][r]) |
                     ((unsigned int)f2bf(v[2 * w2 + 1][r]) << 16);
        *(u32x4*)(buf + row * ROWB + ((16 * gi) ^ ((row & 7) << 4))) = pk;
    }
    // halo rows 0 and 33 (33&7 = 1 -> ^16)
    *(unsigned short*)(buf + 0 * ROWB + (2 * lane)) = f2bf(h[0]);
    *(unsigned short*)(buf + 33 * ROWB + ((2 * lane) ^ 16)) = f2bf(h[1]);
}

// ---- compute one 32-l chunk: 12 x-fragments -> 48 MFMA (4 o-strips) ----
__device__ __forceinline__ void compute_chunk(const char* __restrict__ buf,
                                              const bf16x8 wfrag[4][6],
                                              const float* __restrict__ tb,
                                              float* __restrict__ outb,
                                              int l0, int lane) {
    const int lcol  = lane & 15;
    const int ksub2 = (lane >> 4) * 16;

    f32x4 tv[2];
#pragma unroll
    for (int lt = 0; lt < 2; ++lt)
        tv[lt] = *(const f32x4*)(tb + l0 + lt * 16 + (lane >> 4) * 4);

    f32x4 acc[2][4] = {};
#pragma unroll
    for (int lt = 0; lt < 2; ++lt) {
#pragma unroll
        for (int cc = 0; cc < 6; ++cc) {
            const int k    = cc >> 1;
            const int ih   = cc & 1;
            const int row  = lt * 16 + lcol + k;         // buffer rows 0..33
            const int off  = row * ROWB + ((ih * 64 + ksub2) ^ ((row & 7) << 4));
            const bf16x8 xf = *(const bf16x8*)(buf + off);
#pragma unroll
            for (int s = 0; s < 4; ++s)
                acc[lt][s] = __builtin_amdgcn_mfma_f32_16x16x32_bf16(
                    xf, wfrag[s][cc], acc[lt][s], 0, 0, 0);
        }
    }
#pragma unroll
    for (int s = 0; s < 4; ++s) {
        float* os = outb + (size_t)(s * 16 + lcol) * (NC * NL);
#pragma unroll
        for (int lt = 0; lt < 2; ++lt) {
            const int lq = l0 + lt * 16 + (lane >> 4) * 4;
            f32x4 r;
#pragma unroll
            for (int q = 0; q < 4; ++q) r[q] = acc[lt][s][q] * tv[lt][q];
            *(f32x4*)(os + lq) = r;
        }
    }
}

__global__ __launch_bounds__(128, 2)
void tconv_mfma_kernel(const float* __restrict__ x,
                       const float* __restrict__ tt,
                       const unsigned short* __restrict__ wp,
                       float* __restrict__ out)
{
    __shared__ char lds[WAVES * 2 * BUFB];               // 17 408 B

    const int t    = threadIdx.x;
    const int lane = t & 63;
    const int wave = t >> 6;
    const int c    = blockIdx.y;
    const int b    = blockIdx.z;
    const int lw0  = blockIdx.x * BLKL + wave * WL;      // wave's first l

    char* buf0 = lds + wave * 2 * BUFB;
    char* buf1 = buf0 + BUFB;

    const float* xb = x + ((size_t)b * NI * NC + c) * NL;
    const float* tb = tt + (size_t)(b * NC + c) * NL;
    float* outb = out + ((size_t)b * NO * NC + c) * NL;

    // chunk 0 loads first (HBM critical path)
    f32x4 va[8]; float ha[2];
    stage_load(xb, lw0 + 0 * CL, lane, va, ha);

    // W fragments: all 4 o-strips, 24 coalesced b128 (L2-hot)
    bf16x8 wfrag[4][6];
    {
        const bf16x8* wpb = (const bf16x8*)wp + (size_t)(c * 4 * 6) * 64 + lane;
#pragma unroll
        for (int s = 0; s < 4; ++s)
#pragma unroll
            for (int cc = 0; cc < 6; ++cc)
                wfrag[s][cc] = wpb[(s * 6 + cc) * 64];
    }

    stage_write(buf0, lane, va, ha);

    // barrier-free pipeline: load(t+1) -> compute(t) -> write(t+1)
    f32x4 vb[8]; float hb[2];
    stage_load(xb, lw0 + 1 * CL, lane, vb, hb);
    compute_chunk(buf0, wfrag, tb, outb, lw0 + 0 * CL, lane);
    stage_write(buf1, lane, vb, hb);

    stage_load(xb, lw0 + 2 * CL, lane, va, ha);
    compute_chunk(buf1, wfrag, tb, outb, lw0 + 1 * CL, lane);
    stage_write(buf0, lane, va, ha);

    stage_load(xb, lw0 + 3 * CL, lane, vb, hb);
    compute_chunk(buf0, wfrag, tb, outb, lw0 + 2 * CL, lane);
    stage_write(buf1, lane, vb, hb);

    compute_chunk(buf1, wfrag, tb, outb, lw0 + 3 * CL, lane);
}

extern "C" void kernel_launch(void* const* d_in, const int* in_sizes, int n_in,
                              void* d_out, int out_size, void* d_ws, size_t ws_size,
                              hipStream_t stream) {
    const float* x  = (const float*)d_in[0];
    const float* tt = (const float*)d_in[1];
    const float* w  = (const float*)d_in[2];
    float* out = (float*)d_out;
    unsigned short* wpck = (unsigned short*)d_ws;

    prepack_w_kernel<<<dim3(NO * NI * NC * KW / 256), dim3(256), 0, stream>>>(w, wpck);

    dim3 grid(NL / BLKL, NC, NB);   // (16, 4, 16) = 1024 blocks
    tconv_mfma_kernel<<<grid, dim3(128), 0, stream>>>(x, tt, wpck, out);
}

// Round 10
// 34.896 us; speedup vs baseline: 1.6006x; 1.3307x over previous
//
#include <hip/hip_runtime.h>

// out[b,o,c,l] = time[b,c,l] * sum_{i,k} W[o,i,c,k] * x[b,i,c,l+k-1]  (x zero-padded in l)
// b=16, i=64, c=4, L=4096, o=64, K=3
//
// ONE-BARRIER structure (r8 ablation: skeleton with same loads/stores = 22.4us
// @5.7TB/s; r7's 3-barrier phase convoy is the gap; r9's per-chunk halos
// doubled FETCH - keep block staging). Stage ALL 258 rows (16 f32x4/lane,
// skeleton-proven MLP) -> single lgkm-only barrier -> each wave independently
// computes its own 64-l quarter for ALL 64 o (o-reuse: 1 ds_read : 2 MFMA),
// W in two [2][6] halves to stay <=128 VGPR (4 blocks/CU). Zero further syncs.

#define NB 16
#define NI 64
#define NC 4
#define NL 4096
#define NO 64
#define KW 3
#define LT 64
#define NCH 4
#define LBLK (LT * NCH)       // 256 l per block
#define ROWS (LBLK + 2)       // 258
#define ROWB 128              // 64 i * 2B
#define LDSB (ROWS * ROWB)    // 33024

#define W_PACK_BYTES (NO * NI * NC * KW * 2)   // 98304

typedef float f32x4 __attribute__((ext_vector_type(4)));
typedef short bf16x8 __attribute__((ext_vector_type(8)));
typedef unsigned int u32x2 __attribute__((ext_vector_type(2)));

__device__ inline unsigned short f2bf(float f) {
    unsigned int u = __builtin_bit_cast(unsigned int, f);
    u += 0x7FFFu + ((u >> 16) & 1u);          // round-to-nearest-even
    return (unsigned short)(u >> 16);
}

__device__ __forceinline__ void block_sync_lds() {
    asm volatile("s_waitcnt lgkmcnt(0)" ::: "memory");
    __builtin_amdgcn_s_barrier();
    asm volatile("" ::: "memory");
}

// ---- kernel 1: pack W (coalesced read, scattered 2B write) ----
// dest flat bf16 index = (((c*4 + wv)*6 + cc)*64 + lane)*8 + j  where
// o = wv*16 + (lane&15), i = (cc&1)*32 + (lane>>4)*8 + j, k = cc>>1
__global__ __launch_bounds__(256)
void prepack_w_kernel(const float* __restrict__ w, unsigned short* __restrict__ wp) {
    const int idx = blockIdx.x * 256 + threadIdx.x;      // 49152 = o*i*c*k
    const float v = w[idx];                              // coalesced
    const int k = idx % 3;
    int r = idx / 3;
    const int c = r & 3;  r >>= 2;
    const int i = r & 63;
    const int o = r >> 6;
    const int cc   = k * 2 + (i >> 5);
    const int lane = (((i >> 3) & 3) << 4) | (o & 15);
    const int j    = i & 7;
    const int wv   = o >> 4;
    wp[(((c * 4 + wv) * 6 + cc) * 64 + lane) * 8 + j] = f2bf(v);
}

// staging task: q = lane&15 (l-quad), g = wave*4 + (lane>>4) (i-group of 4)
__device__ __forceinline__ void stage_load(const float* __restrict__ xb,
                                           int l0, int g, f32x4 s[4]) {
    const float* p = xb + (size_t)(4 * g) * (NC * NL) + l0;
    s[0] = *(const f32x4*)(p);
    s[1] = *(const f32x4*)(p + NC * NL);
    s[2] = *(const f32x4*)(p + 2 * NC * NL);
    s[3] = *(const f32x4*)(p + 3 * NC * NL);
}

__device__ __forceinline__ void stage_write(char* __restrict__ lds,
                                            int r0, int g, const f32x4 s[4]) {
#pragma unroll
    for (int r = 0; r < 4; ++r) {
        const int rr = r0 + r;
        u32x2 pk;
        pk[0] = (unsigned int)f2bf(s[0][r]) | ((unsigned int)f2bf(s[1][r]) << 16);
        pk[1] = (unsigned int)f2bf(s[2][r]) | ((unsigned int)f2bf(s[3][r]) << 16);
        *(u32x2*)(lds + rr * ROWB + ((8 * g) ^ ((rr & 7) << 4))) = pk;
    }
}

__global__ __launch_bounds__(256, 4)
void tconv_mfma_kernel(const float* __restrict__ x,
                       const float* __restrict__ tt,
                       const unsigned short* __restrict__ wp,
                       float* __restrict__ out)
{
    __shared__ char lds[LDSB];                           // 33 024 B

    const int t    = threadIdx.x;
    const int lane = t & 63;
    const int wave = t >> 6;
    const int c    = blockIdx.y;
    const int b    = blockIdx.z;
    const int lb0  = blockIdx.x * LBLK;
    const int g    = wave * 4 + (lane >> 4);
    const int lq   = 4 * (lane & 15);

    const float* xb = x + ((size_t)b * NI * NC + c) * NL;
    const float* tb = tt + (size_t)(b * NC + c) * NL;

    // ---- mega-stage: ALL 4 chunks' loads issued up front (max MLP) ----
    f32x4 s[4][4];
#pragma unroll
    for (int ch = 0; ch < NCH; ++ch)
        stage_load(xb, lb0 + ch * LT + lq, g, s[ch]);
    float h = 0.f; int hrow = 0, hcol = 0;
    if (t < 128) {                                       // halo rows 0 and 257
        const int which = t & 1;
        const int i     = t >> 1;
        hrow = which ? (LBLK + 1) : 0;
        hcol = 2 * i;
        const int lh = which ? (lb0 + LBLK) : (lb0 - 1);
        if (lh >= 0 && lh < NL) h = xb[(size_t)i * (NC * NL) + lh];
    }

#pragma unroll
    for (int ch = 0; ch < NCH; ++ch)
        stage_write(lds, 1 + ch * LT + lq, g, s[ch]);
    if (t < 128)
        *(unsigned short*)(lds + hrow * ROWB + (hcol ^ ((hrow & 7) << 4))) = f2bf(h);

    block_sync_lds();                                    // the ONLY barrier

    // ---- per-wave independent compute: wave owns l-range [wave*64, +64), all o
    const int lcol  = lane & 15;
    const int ksub2 = (lane >> 4) * 16;
    const int rbase = wave * LT;                         // buffer row base
    const int lwave = lb0 + wave * LT;

#pragma unroll
    for (int hh = 0; hh < 2; ++hh) {                     // o halves (32 o each)
        bf16x8 wfrag[2][6];
        {
            const bf16x8* wpb = (const bf16x8*)wp
                + (size_t)((c * 4 + 2 * hh) * 6) * 64 + lane;
#pragma unroll
            for (int s2 = 0; s2 < 2; ++s2)
#pragma unroll
                for (int cc = 0; cc < 6; ++cc)
                    wfrag[s2][cc] = wpb[(s2 * 6 + cc) * 64];
        }
#pragma unroll
        for (int lt = 0; lt < 4; ++lt) {
            const int l0 = lwave + lt * 16 + (lane >> 4) * 4;
            const f32x4 tv = *(const f32x4*)(tb + l0);
            f32x4 acc[2] = {};
#pragma unroll
            for (int cc = 0; cc < 6; ++cc) {
                const int k   = cc >> 1;
                const int ih  = cc & 1;
                const int row = rbase + lt * 16 + lcol + k;
                const int off = row * ROWB + ((ih * 64 + ksub2) ^ ((row & 7) << 4));
                const bf16x8 xf = *(const bf16x8*)(lds + off);
                acc[0] = __builtin_amdgcn_mfma_f32_16x16x32_bf16(xf, wfrag[0][cc], acc[0], 0, 0, 0);
                acc[1] = __builtin_amdgcn_mfma_f32_16x16x32_bf16(xf, wfrag[1][cc], acc[1], 0, 0, 0);
            }
#pragma unroll
            for (int s2 = 0; s2 < 2; ++s2) {
                const int o = (2 * hh + s2) * 16 + lcol;
                float* os = out + ((size_t)b * NO * NC + (size_t)o * NC + c) * NL;
                f32x4 r;
#pragma unroll
                for (int q = 0; q < 4; ++q) r[q] = acc[s2][q] * tv[q];
                *(f32x4*)(os + l0) = r;
            }
        }
    }
}

extern "C" void kernel_launch(void* const* d_in, const int* in_sizes, int n_in,
                              void* d_out, int out_size, void* d_ws, size_t ws_size,
                              hipStream_t stream) {
    const float* x  = (const float*)d_in[0];
    const float* tt = (const float*)d_in[1];
    const float* w  = (const float*)d_in[2];
    float* out = (float*)d_out;
    unsigned short* wpck = (unsigned short*)d_ws;

    prepack_w_kernel<<<dim3(NO * NI * NC * KW / 256), dim3(256), 0, stream>>>(w, wpck);

    dim3 grid(NL / LBLK, NC, NB);   // (16, 4, 16) = 1024 blocks
    tconv_mfma_kernel<<<grid, dim3(256), 0, stream>>>(x, tt, wpck, out);
}

// Round 11
// 33.052 us; speedup vs baseline: 1.6899x; 1.0558x over previous
//
#include <hip/hip_runtime.h>

// out[b,o,c,l] = time[b,c,l] * sum_{i,k} W[o,i,c,k] * x[b,i,c,l+k-1]  (x zero-padded in l)
// b=16, i=64, c=4, L=4096, o=64, K=3
//
// STEADY-STATE pipeline (r8 skeleton = 22.4us with reads+writes continuously
// overlapped; all phase-structured variants = ~31us). Block = (b,c,256 l) as
// 8 chunks of 32 l, ONE contiguous 258-row LDS tile (halos free), stage-ahead
// -by-2: iterations 0..5 run load(c+2) || compute(c)+store(c) || write(c+2),
// so each CU keeps both HBM streams busy simultaneously. lgkm-only barriers
// (stores/prefetch never drained). W prepacked; float4 epilogue.

#define NB 16
#define NI 64
#define NC 4
#define NL 4096
#define NO 64
#define KW 3
#define LT 32                 // chunk length
#define NCH 8                 // chunks per block
#define LBLK (LT * NCH)       // 256 l per block
#define ROWS (LBLK + 2)       // 258
#define ROWB 128              // 64 i * 2B
#define LDSB (ROWS * ROWB)    // 33024

#define W_PACK_BYTES (NO * NI * NC * KW * 2)   // 98304

typedef float f32x4 __attribute__((ext_vector_type(4)));
typedef short bf16x8 __attribute__((ext_vector_type(8)));

__device__ inline unsigned short f2bf(float f) {
    unsigned int u = __builtin_bit_cast(unsigned int, f);
    u += 0x7FFFu + ((u >> 16) & 1u);          // round-to-nearest-even
    return (unsigned short)(u >> 16);
}

__device__ __forceinline__ void block_sync_lds() {
    asm volatile("s_waitcnt lgkmcnt(0)" ::: "memory");
    __builtin_amdgcn_s_barrier();
    asm volatile("" ::: "memory");
}

// ---- kernel 1: pack W (coalesced read, scattered 2B write) ----
// dest flat bf16 index = (((c*4 + wv)*6 + cc)*64 + lane)*8 + j  where
// o = wv*16 + (lane&15), i = (cc&1)*32 + (lane>>4)*8 + j, k = cc>>1
__global__ __launch_bounds__(256)
void prepack_w_kernel(const float* __restrict__ w, unsigned short* __restrict__ wp) {
    const int idx = blockIdx.x * 256 + threadIdx.x;      // 49152 = o*i*c*k
    const float v = w[idx];                              // coalesced
    const int k = idx % 3;
    int r = idx / 3;
    const int c = r & 3;  r >>= 2;
    const int i = r & 63;
    const int o = r >> 6;
    const int cc   = k * 2 + (i >> 5);
    const int lane = (((i >> 3) & 3) << 4) | (o & 15);
    const int j    = i & 7;
    const int wv   = o >> 4;
    wp[(((c * 4 + wv) * 6 + cc) * 64 + lane) * 8 + j] = f2bf(v);
}

// ---- staging: per chunk, thread (g2 = t>>3 in [0,32): 2-i group, q = t&7:
// l-quad) loads 2 f32x4 (2 i-rows, same l-quad) and writes 4 u32 LDS rows.
__device__ __forceinline__ void stage_load(const float* __restrict__ xb,
                                           int l0q, int g2, f32x4 s[2]) {
    const float* p = xb + (size_t)(2 * g2) * (NC * NL) + l0q;
    s[0] = *(const f32x4*)(p);
    s[1] = *(const f32x4*)(p + NC * NL);
}

__device__ __forceinline__ void stage_write(char* __restrict__ lds,
                                            int ch, int q, int g2,
                                            const f32x4 s[2]) {
#pragma unroll
    for (int r = 0; r < 4; ++r) {
        const int row = ch * LT + 4 * q + r + 1;         // rows 1..256
        const unsigned int pk =
            (unsigned int)f2bf(s[0][r]) | ((unsigned int)f2bf(s[1][r]) << 16);
        *(unsigned int*)(lds + row * ROWB + ((4 * g2) ^ ((row & 7) << 4))) = pk;
    }
}

// ---- compute one 32-l chunk: wave owns 16 o (o0 = wave*16), 2 l-subtiles
__device__ __forceinline__ void compute_chunk(const char* __restrict__ lds,
                                              const bf16x8 wfrag[6],
                                              const float* __restrict__ tb,
                                              float* __restrict__ ob,
                                              int ch, int lb0, int lane) {
    const int lcol  = lane & 15;
    const int ksub2 = (lane >> 4) * 16;
#pragma unroll
    for (int lt = 0; lt < 2; ++lt) {
        const int l0 = lb0 + ch * LT + lt * 16 + (lane >> 4) * 4;
        const f32x4 tv = *(const f32x4*)(tb + l0);
        f32x4 acc = {};
#pragma unroll
        for (int cc = 0; cc < 6; ++cc) {
            const int row = ch * LT + lt * 16 + lcol + (cc >> 1);
            const int off = row * ROWB + ((((cc & 1) << 6) + ksub2) ^ ((row & 7) << 4));
            const bf16x8 xf = *(const bf16x8*)(lds + off);
            acc = __builtin_amdgcn_mfma_f32_16x16x32_bf16(xf, wfrag[cc], acc, 0, 0, 0);
        }
        f32x4 r;
#pragma unroll
        for (int qq = 0; qq < 4; ++qq) r[qq] = acc[qq] * tv[qq];
        *(f32x4*)(ob + l0) = r;
    }
}

__global__ __launch_bounds__(256, 4)
void tconv_mfma_kernel(const float* __restrict__ x,
                       const float* __restrict__ tt,
                       const unsigned short* __restrict__ wp,
                       float* __restrict__ out)
{
    __shared__ char lds[LDSB];                           // 33 024 B

    const int t    = threadIdx.x;
    const int lane = t & 63;
    const int wave = t >> 6;
    const int c    = blockIdx.y;
    const int b    = blockIdx.z;
    const int lb0  = blockIdx.x * LBLK;
    const int g2   = t >> 3;                             // 0..31
    const int q    = t & 7;                              // 0..7
    const int lq   = 4 * q;

    const float* xb = x + ((size_t)b * NI * NC + c) * NL;
    const float* tb = tt + (size_t)(b * NC + c) * NL;
    float* ob = out + ((size_t)b * NO * NC
                       + (size_t)(wave * 16 + (lane & 15)) * NC + c) * NL;

    // ---- prologue: chunks 0,1 + halo loads first (HBM critical path)
    f32x4 sA[2], sB[2];
    stage_load(xb, lb0 + 0 * LT + lq, g2, sA);
    stage_load(xb, lb0 + 1 * LT + lq, g2, sB);
    float h = 0.f; int hrow = 0, hcol = 0;
    if (t < 128) {                                       // halo rows 0 and 257
        const int which = t & 1;
        const int i     = t >> 1;
        hrow = which ? (LBLK + 1) : 0;
        hcol = 2 * i;
        const int lh = which ? (lb0 + LBLK) : (lb0 - 1);
        if (lh >= 0 && lh < NL) h = xb[(size_t)i * (NC * NL) + lh];
    }

    // W fragments: 6 coalesced b128, L2-hot
    bf16x8 wfrag[6];
    {
        const bf16x8* wpb = (const bf16x8*)wp + (size_t)((c * 4 + wave) * 6) * 64 + lane;
#pragma unroll
        for (int cc = 0; cc < 6; ++cc) wfrag[cc] = wpb[cc * 64];
    }

    stage_write(lds, 0, q, g2, sA);
    stage_write(lds, 1, q, g2, sB);
    if (t < 128)
        *(unsigned short*)(lds + hrow * ROWB + (hcol ^ ((hrow & 7) << 4))) = f2bf(h);
    block_sync_lds();

    // ---- steady state: 6 of 8 iterations overlap load || compute+store || write
#pragma unroll
    for (int cn = 0; cn < NCH - 2; ++cn) {
        if ((cn & 1) == 0) {
            stage_load(xb, lb0 + (cn + 2) * LT + lq, g2, sA);
            compute_chunk(lds, wfrag, tb, ob, cn, lb0, lane);
            stage_write(lds, cn + 2, q, g2, sA);
        } else {
            stage_load(xb, lb0 + (cn + 2) * LT + lq, g2, sB);
            compute_chunk(lds, wfrag, tb, ob, cn, lb0, lane);
            stage_write(lds, cn + 2, q, g2, sB);
        }
        block_sync_lds();
    }

    // ---- drain
    compute_chunk(lds, wfrag, tb, ob, NCH - 2, lb0, lane);
    compute_chunk(lds, wfrag, tb, ob, NCH - 1, lb0, lane);
}

extern "C" void kernel_launch(void* const* d_in, const int* in_sizes, int n_in,
                              void* d_out, int out_size, void* d_ws, size_t ws_size,
                              hipStream_t stream) {
    const float* x  = (const float*)d_in[0];
    const float* tt = (const float*)d_in[1];
    const float* w  = (const float*)d_in[2];
    float* out = (float*)d_out;
    unsigned short* wpck = (unsigned short*)d_ws;

    prepack_w_kernel<<<dim3(NO * NI * NC * KW / 256), dim3(256), 0, stream>>>(w, wpck);

    dim3 grid(NL / LBLK, NC, NB);   // (16, 4, 16) = 1024 blocks
    tconv_mfma_kernel<<<grid, dim3(256), 0, stream>>>(x, tt, wpck, out);
}